// Round 8
// baseline (225.985 us; speedup 1.0000x reference)
//
#include <hip/hip_runtime.h>
#include <hip/hip_fp16.h>

typedef _Float16 half8 __attribute__((ext_vector_type(8)));
typedef float    f32x4 __attribute__((ext_vector_type(4)));

#define EPSL 0.1f
#define LDSW 68   // staging row stride (uints): 272B, 16B-aligned, 2-way banks (free)
#define LDSW2 36  // h0 row stride (uints): 144B, 16B-aligned, 2-way banks (free)

__device__ __forceinline__ float fast_tanh(float x) {
    float e = __expf(2.0f * x);
    return 1.0f - 2.0f * __builtin_amdgcn_rcpf(e + 1.0f);
}

// v_cvt_pkrtz_f16_f32: pack two f32 into one uint (lo=a, hi=b), 1 inst.
__device__ __forceinline__ unsigned int pk2(float a, float b) {
    union { __fp16 __attribute__((ext_vector_type(2))) h; unsigned int u; } v;
    v.h = __builtin_amdgcn_cvt_pkrtz(a, b);
    return v.u;
}
__device__ __forceinline__ float2 unpk2(unsigned int u) {
    union { unsigned int u; __half2 h; } v; v.u = u;
    return __half22float2(v.h);
}

// Pre-pack W1/W2 (fp32 -> fp16) into MFMA fragment layouts in d_ws.
// mat 0: W1 as B-frag  (GEMM1: z1 = h0 @ W1)
// mat 1: W2 as B-frag  (GEMM2: z2 = h1 @ W2)
// mat 2: W2T as B-frag (GEMM3: g1 = dz2 @ W2T)
// mat 3: W1 as A-frag  (GEMM4: g0T = W1 @ dz1T)
// A[m=lane&15][k=(lane>>4)*8+j]; B[k=(lane>>4)*8+j][n=lane&15];
// stored lane-contiguous: pk[((mat*2+kt)*4+nt)*512 + lane*8 + j].
__global__ void pack_weights(const float* __restrict__ W1,
                             const float* __restrict__ W2,
                             _Float16* __restrict__ pk) {
    const int t = threadIdx.x;        // 0..63
    const int q = t >> 4, r = t & 15;
    for (int kt = 0; kt < 2; ++kt)
        for (int nt = 0; nt < 4; ++nt)
            for (int j = 0; j < 8; ++j) {
                const int k = kt * 32 + q * 8 + j;
                const int n = nt * 16 + r;   // plays role of m for mat 3
                const int base = ((kt * 4 + nt) * 64 + t) * 8 + j;
                pk[0 * 4096 + base] = (_Float16)W1[k * 64 + n];
                pk[1 * 4096 + base] = (_Float16)W2[k * 64 + n];
                pk[2 * 4096 + base] = (_Float16)W2[n * 64 + k];
                pk[3 * 4096 + base] = (_Float16)W1[n * 64 + k];
            }
}

extern "C" __global__ void __launch_bounds__(256, 6)
lnn_mfma(const float* __restrict__ x,
         const float* __restrict__ W0, const float* __restrict__ b0,
         const float* __restrict__ b1, const float* __restrict__ b2,
         const float* __restrict__ W3,
         const _Float16* __restrict__ pk,
         float* __restrict__ out)
{
    // 4 independent waves per block; wave w owns rows [w*16, w*16+16).
    __shared__ unsigned int lds [64 * LDSW];   // (value, tangent) half2 staging
    __shared__ unsigned int lds2[64 * LDSW2];  // h0 pairs (2 features/uint), row=sample

    const int t    = threadIdx.x & 63;
    const int w    = threadIdx.x >> 6;
    const int q    = t >> 4;
    const int r    = t & 15;
    const int wrow = w * 16;
    const long sbase = (long)blockIdx.x * 64 + wrow;  // this wave's 16 samples

    const float2 xv = *(const float2*)(x + 2 * (sbase + r));
    const float x0 = xv.x, x1 = xv.y;

    auto ldpk = [&](int mat, int kt, int nt) -> half8 {
        return *(const half8*)(pk + ((mat * 2 + kt) * 4 + nt) * 512 + t * 8);
    };
    // LDS C->frag: 8 half2 at (row, k=kt*32+q*8..+7) -> value frag + tangent frag
    auto ldfrag = [&](int row, int kt, half8& vf, half8& tf) {
        const int off = row * LDSW + kt * 32 + q * 8;
        const uint4 A = *(const uint4*)&lds[off];
        const uint4 B = *(const uint4*)&lds[off + 4];
        union { unsigned int u[4]; half8 h; } cv, ct;
        cv.u[0] = __builtin_amdgcn_perm(A.y, A.x, 0x05040100u);
        cv.u[1] = __builtin_amdgcn_perm(A.w, A.z, 0x05040100u);
        cv.u[2] = __builtin_amdgcn_perm(B.y, B.x, 0x05040100u);
        cv.u[3] = __builtin_amdgcn_perm(B.w, B.z, 0x05040100u);
        ct.u[0] = __builtin_amdgcn_perm(A.y, A.x, 0x07060302u);
        ct.u[1] = __builtin_amdgcn_perm(A.w, A.z, 0x07060302u);
        ct.u[2] = __builtin_amdgcn_perm(B.y, B.x, 0x07060302u);
        ct.u[3] = __builtin_amdgcn_perm(B.w, B.z, 0x07060302u);
        vf = cv.h; tf = ct.h;
    };

    // ---------------- P0: h0/th0 in A-frag layout; stage h0 pairs (frag words) to lds2
    half8 ah0[2], at0[2];
    #pragma unroll
    for (int kt = 0; kt < 2; ++kt) {
        const int f = kt * 32 + q * 8;
        const float4 waA = *(const float4*)(W0 + f);
        const float4 waB = *(const float4*)(W0 + f + 4);
        const float4 wbA = *(const float4*)(W0 + 64 + f);
        const float4 wbB = *(const float4*)(W0 + 64 + f + 4);
        const float4 bbA = *(const float4*)(b0 + f);
        const float4 bbB = *(const float4*)(b0 + f + 4);
        const float wa[8] = {waA.x, waA.y, waA.z, waA.w, waB.x, waB.y, waB.z, waB.w};
        const float wb[8] = {wbA.x, wbA.y, wbA.z, wbA.w, wbB.x, wbB.y, wbB.z, wbB.w};
        const float bb[8] = {bbA.x, bbA.y, bbA.z, bbA.w, bbB.x, bbB.y, bbB.z, bbB.w};
        float h0v[8], t0v[8];
        #pragma unroll
        for (int j = 0; j < 8; ++j) {
            const float z0 = fmaf(x0, wa[j], fmaf(x1, wb[j], bb[j]));
            const float h0 = fast_tanh(z0);
            h0v[j] = h0;
            t0v[j] = fmaf(-h0, h0, 1.0f) * wb[j];
        }
        union { unsigned int u[4]; half8 h; } ph, pt;
        #pragma unroll
        for (int p = 0; p < 4; ++p) {
            ph.u[p] = pk2(h0v[2 * p], h0v[2 * p + 1]);
            pt.u[p] = pk2(t0v[2 * p], t0v[2 * p + 1]);
        }
        // frag h-pair words double as the h0 staging format (2 features/uint)
        *(uint4*)&lds2[(wrow + r) * LDSW2 + kt * 16 + q * 4] = *(const uint4*)ph.u;
        ah0[kt] = ph.h; at0[kt] = pt.h;
    }

    // ---------------- GEMM1: z1 = h0 @ W1 ; tz1 = th0 @ W1
    f32x4 acc[4], tacc[4];
    #pragma unroll
    for (int nt = 0; nt < 4; ++nt) { acc[nt] = (f32x4){0,0,0,0}; tacc[nt] = (f32x4){0,0,0,0}; }
    #pragma unroll
    for (int kt = 0; kt < 2; ++kt)
        #pragma unroll
        for (int nt = 0; nt < 4; ++nt) {
            const half8 bw = ldpk(0, kt, nt);
            acc[nt]  = __builtin_amdgcn_mfma_f32_16x16x32_f16(ah0[kt], bw, acc[nt], 0, 0, 0);
            tacc[nt] = __builtin_amdgcn_mfma_f32_16x16x32_f16(at0[kt], bw, tacc[nt], 0, 0, 0);
        }

    // ---------------- P1: h1/th1 at (sample=q*4+g, f1=nt*16+r); keep + LDS
    unsigned int h1p[4][4];
    #pragma unroll
    for (int nt = 0; nt < 4; ++nt) {
        const float b1f = b1[nt * 16 + r];
        #pragma unroll
        for (int g = 0; g < 4; ++g) {
            const float z1 = acc[nt][g] + b1f;
            const float h1 = fast_tanh(z1);
            const float th1 = fmaf(-h1, h1, 1.0f) * tacc[nt][g];
            const unsigned int u = pk2(h1, th1);
            h1p[nt][g] = u;
            lds[(wrow + q * 4 + g) * LDSW + nt * 16 + r] = u;
        }
    }
    __builtin_amdgcn_wave_barrier();

    // ---------------- GEMM2: z2 = h1 @ W2 ; tz2 = th1 @ W2
    #pragma unroll
    for (int nt = 0; nt < 4; ++nt) { acc[nt] = (f32x4){0,0,0,0}; tacc[nt] = (f32x4){0,0,0,0}; }
    #pragma unroll
    for (int kt = 0; kt < 2; ++kt) {
        half8 av, at;
        ldfrag(wrow + r, kt, av, at);
        #pragma unroll
        for (int nt = 0; nt < 4; ++nt) {
            const half8 bw = ldpk(1, kt, nt);
            acc[nt]  = __builtin_amdgcn_mfma_f32_16x16x32_f16(av, bw, acc[nt], 0, 0, 0);
            tacc[nt] = __builtin_amdgcn_mfma_f32_16x16x32_f16(at, bw, tacc[nt], 0, 0, 0);
        }
    }
    __builtin_amdgcn_wave_barrier();

    // ---------------- P2: dz2 = W3*A2 ; tdz2 = -2*h2*dz2*tz2 -> LDS
    #pragma unroll
    for (int nt = 0; nt < 4; ++nt) {
        const float b2f = b2[nt * 16 + r];
        const float w3f = W3[nt * 16 + r];
        #pragma unroll
        for (int g = 0; g < 4; ++g) {
            const float z2 = acc[nt][g] + b2f;
            const float h2 = fast_tanh(z2);
            const float A2 = fmaf(-h2, h2, 1.0f);
            const float dz2 = w3f * A2;
            const float t1  = h2 * tacc[nt][g];
            const float td2 = -2.0f * (dz2 * t1);
            lds[(wrow + q * 4 + g) * LDSW + nt * 16 + r] = pk2(dz2, td2);
        }
    }
    __builtin_amdgcn_wave_barrier();

    // ---------------- GEMM3: g1 = dz2 @ W2T ; tg1 = tdz2 @ W2T
    #pragma unroll
    for (int nt = 0; nt < 4; ++nt) { acc[nt] = (f32x4){0,0,0,0}; tacc[nt] = (f32x4){0,0,0,0}; }
    #pragma unroll
    for (int kt = 0; kt < 2; ++kt) {
        half8 av, at;
        ldfrag(wrow + r, kt, av, at);
        #pragma unroll
        for (int nt = 0; nt < 4; ++nt) {
            const half8 bw = ldpk(2, kt, nt);
            acc[nt]  = __builtin_amdgcn_mfma_f32_16x16x32_f16(av, bw, acc[nt], 0, 0, 0);
            tacc[nt] = __builtin_amdgcn_mfma_f32_16x16x32_f16(at, bw, tacc[nt], 0, 0, 0);
        }
    }
    __builtin_amdgcn_wave_barrier();

    // ---------------- P3: dz1 = g1*A1 ; tdz1 = tg1*A1 - 2*g1*h1*th1 -> LDS
    #pragma unroll
    for (int nt = 0; nt < 4; ++nt)
        #pragma unroll
        for (int g = 0; g < 4; ++g) {
            const float g1 = acc[nt][g];
            const float tg1 = tacc[nt][g];
            const float2 ht = unpk2(h1p[nt][g]);
            const float A1 = fmaf(-ht.x, ht.x, 1.0f);
            const float d1 = g1 * A1;
            const float u = g1 * ht.x * ht.y;
            const float td1 = fmaf(tg1, A1, -2.0f * u);
            lds[(wrow + q * 4 + g) * LDSW + nt * 16 + r] = pk2(d1, td1);
        }
    __builtin_amdgcn_wave_barrier();

    // ---------------- GEMM4 (transposed): g0T = W1 @ dz1T ; tg0T = W1 @ tdz1T
    #pragma unroll
    for (int mt = 0; mt < 4; ++mt) { acc[mt] = (f32x4){0,0,0,0}; tacc[mt] = (f32x4){0,0,0,0}; }
    #pragma unroll
    for (int kt = 0; kt < 2; ++kt) {
        half8 bd, btd;
        ldfrag(wrow + r, kt, bd, btd);
        #pragma unroll
        for (int mt = 0; mt < 4; ++mt) {
            const half8 aw = ldpk(3, kt, mt);
            acc[mt]  = __builtin_amdgcn_mfma_f32_16x16x32_f16(aw, bd,  acc[mt], 0, 0, 0);
            tacc[mt] = __builtin_amdgcn_mfma_f32_16x16x32_f16(aw, btd, tacc[mt], 0, 0, 0);
        }
    }

    // ---------------- P4: read staged h0 pairs, recompute th0 = (1-h0^2)*wb,
    // fold into 3 dots; reduce over features: 16 in-lane + shfl_xor(16,32).
    float pg = 0.f, ph0 = 0.f, ph1 = 0.f;
    #pragma unroll
    for (int mt = 0; mt < 4; ++mt) {
        const int f = mt * 16 + q * 4;
        const float4 waF = *(const float4*)(W0 + f);
        const float4 wbF = *(const float4*)(W0 + 64 + f);
        const float wa[4] = {waF.x, waF.y, waF.z, waF.w};
        const float wb[4] = {wbF.x, wbF.y, wbF.z, wbF.w};
        // features f..f+3 = 2 packed uints at col mt*8 + q*2
        const uint2 hh = *(const uint2*)&lds2[(wrow + r) * LDSW2 + mt * 8 + q * 2];
        const float2 hA = unpk2(hh.x);   // h0 for g=0,1
        const float2 hB = unpk2(hh.y);   // h0 for g=2,3
        const float h0v[4] = {hA.x, hA.y, hB.x, hB.y};
        #pragma unroll
        for (int g = 0; g < 4; ++g) {
            const float h0 = h0v[g];
            const float A0 = fmaf(-h0, h0, 1.0f);
            const float th0 = A0 * wb[g];
            const float g0 = acc[mt][g];
            const float tg0 = tacc[mt][g];
            const float d0 = g0 * A0;
            const float u = g0 * h0 * th0;
            const float td0 = fmaf(-2.0f, u, tg0 * A0);
            pg  = fmaf(wa[g], d0, pg);
            ph0 = fmaf(wa[g], td0, ph0);
            ph1 = fmaf(wb[g], td0, ph1);
        }
    }
    pg  += __shfl_xor(pg, 16);  pg  += __shfl_xor(pg, 32);
    ph0 += __shfl_xor(ph0, 16); ph0 += __shfl_xor(ph0, 32);
    ph1 += __shfl_xor(ph1, 16); ph1 += __shfl_xor(ph1, 32);
    if (q == 0) {
        const float num = fmaf(-ph0, x1, pg);
        const float a = num / (ph1 + EPSL);
        float2 o;
        o.x = x1;
        o.y = a;
        *(float2*)(out + 2 * (sbase + r)) = o;
    }
}

extern "C" void kernel_launch(void* const* d_in, const int* in_sizes, int n_in,
                              void* d_out, int out_size, void* d_ws, size_t ws_size,
                              hipStream_t stream) {
    // setup_inputs order: t, x, W0, b0, W1, b1, W2, b2, W3, b3
    const float* x  = (const float*)d_in[1];
    const float* W0 = (const float*)d_in[2];
    const float* b0 = (const float*)d_in[3];
    const float* W1 = (const float*)d_in[4];
    const float* b1 = (const float*)d_in[5];
    const float* W2 = (const float*)d_in[6];
    const float* b2 = (const float*)d_in[7];
    const float* W3 = (const float*)d_in[8];
    // b3 unused (no effect on grad/Hessian)

    _Float16* pk = (_Float16*)d_ws;   // 4 mats * 4096 halfs = 32 KB
    const int B = in_sizes[1] / 2;    // 1048576

    pack_weights<<<1, 64, 0, stream>>>(W1, W2, pk);
    // 256-thread blocks = 4 independent waves x 16 samples each
    lnn_mfma<<<B / 64, 256, 0, stream>>>(x, W0, b0, b1, b2, W3, pk, (float*)d_out);
}

// Round 9
// 219.988 us; speedup vs baseline: 1.0273x; 1.0273x over previous
//
#include <hip/hip_runtime.h>
#include <hip/hip_fp16.h>

typedef _Float16 half8 __attribute__((ext_vector_type(8)));
typedef float    f32x4 __attribute__((ext_vector_type(4)));

#define EPSL 0.1f
#define LDSW 68   // staging row stride (uints): 272B, 16B-aligned, 2-way banks (free)
#define LDSW2 36  // h0 row stride (uints): 144B, 16B-aligned, 2-way banks (free)

__device__ __forceinline__ float fast_tanh(float x) {
    float e = __expf(2.0f * x);
    return 1.0f - 2.0f * __builtin_amdgcn_rcpf(e + 1.0f);
}

// v_cvt_pkrtz_f16_f32: pack two f32 into one uint (lo=a, hi=b), 1 inst.
__device__ __forceinline__ unsigned int pk2(float a, float b) {
    union { __fp16 __attribute__((ext_vector_type(2))) h; unsigned int u; } v;
    v.h = __builtin_amdgcn_cvt_pkrtz(a, b);
    return v.u;
}
__device__ __forceinline__ float2 unpk2(unsigned int u) {
    union { unsigned int u; __half2 h; } v; v.u = u;
    return __half22float2(v.h);
}

// Pre-pack W1/W2 (fp32 -> fp16) into MFMA fragment layouts in d_ws.
// mat 0: W1 as B-frag  (GEMM1: z1 = h0 @ W1)
// mat 1: W2 as B-frag  (GEMM2: z2 = h1 @ W2)
// mat 2: W2T as B-frag (GEMM3: g1 = dz2 @ W2T)
// mat 3: W1 as A-frag  (GEMM4: g0T = W1 @ dz1T)
// A[m=lane&15][k=(lane>>4)*8+j]; B[k=(lane>>4)*8+j][n=lane&15];
// stored lane-contiguous: pk[((mat*2+kt)*4+nt)*512 + lane*8 + j].
__global__ void pack_weights(const float* __restrict__ W1,
                             const float* __restrict__ W2,
                             _Float16* __restrict__ pk) {
    const int t = threadIdx.x;        // 0..63
    const int q = t >> 4, r = t & 15;
    for (int kt = 0; kt < 2; ++kt)
        for (int nt = 0; nt < 4; ++nt)
            for (int j = 0; j < 8; ++j) {
                const int k = kt * 32 + q * 8 + j;
                const int n = nt * 16 + r;   // plays role of m for mat 3
                const int base = ((kt * 4 + nt) * 64 + t) * 8 + j;
                pk[0 * 4096 + base] = (_Float16)W1[k * 64 + n];
                pk[1 * 4096 + base] = (_Float16)W2[k * 64 + n];
                pk[2 * 4096 + base] = (_Float16)W2[n * 64 + k];
                pk[3 * 4096 + base] = (_Float16)W1[n * 64 + k];
            }
}

// launch_bounds(256,4): VGPR cap 128 — natural allocation (~60-72), no spills
// (R8's (256,6) squeezed to 40 VGPR and spilled: WRITE_SIZE 8.2->14.3 MB, dur
// regressed 166->174). LDS 26.6 KB still lets HW fit 6 blocks/CU.
extern "C" __global__ void __launch_bounds__(256, 4)
lnn_mfma(const float* __restrict__ x,
         const float* __restrict__ W0, const float* __restrict__ b0,
         const float* __restrict__ b1, const float* __restrict__ b2,
         const float* __restrict__ W3,
         const _Float16* __restrict__ pk,
         float* __restrict__ out)
{
    // 4 independent waves per block; wave w owns rows [w*16, w*16+16).
    __shared__ unsigned int lds [64 * LDSW];   // (value, tangent) half2 staging
    __shared__ unsigned int lds2[64 * LDSW2];  // h0 pairs (2 features/uint), row=sample

    const int t    = threadIdx.x & 63;
    const int w    = threadIdx.x >> 6;
    const int q    = t >> 4;
    const int r    = t & 15;
    const int wrow = w * 16;
    const long sbase = (long)blockIdx.x * 64 + wrow;  // this wave's 16 samples

    const float2 xv = *(const float2*)(x + 2 * (sbase + r));
    const float x0 = xv.x, x1 = xv.y;

    auto ldpk = [&](int mat, int kt, int nt) -> half8 {
        return *(const half8*)(pk + ((mat * 2 + kt) * 4 + nt) * 512 + t * 8);
    };
    // LDS C->frag: 8 half2 at (row, k=kt*32+q*8..+7) -> value frag + tangent frag
    auto ldfrag = [&](int row, int kt, half8& vf, half8& tf) {
        const int off = row * LDSW + kt * 32 + q * 8;
        const uint4 A = *(const uint4*)&lds[off];
        const uint4 B = *(const uint4*)&lds[off + 4];
        union { unsigned int u[4]; half8 h; } cv, ct;
        cv.u[0] = __builtin_amdgcn_perm(A.y, A.x, 0x05040100u);
        cv.u[1] = __builtin_amdgcn_perm(A.w, A.z, 0x05040100u);
        cv.u[2] = __builtin_amdgcn_perm(B.y, B.x, 0x05040100u);
        cv.u[3] = __builtin_amdgcn_perm(B.w, B.z, 0x05040100u);
        ct.u[0] = __builtin_amdgcn_perm(A.y, A.x, 0x07060302u);
        ct.u[1] = __builtin_amdgcn_perm(A.w, A.z, 0x07060302u);
        ct.u[2] = __builtin_amdgcn_perm(B.y, B.x, 0x07060302u);
        ct.u[3] = __builtin_amdgcn_perm(B.w, B.z, 0x07060302u);
        vf = cv.h; tf = ct.h;
    };

    // ---------------- P0: h0/th0 in A-frag layout; stage h0 pairs (frag words) to lds2
    half8 ah0[2], at0[2];
    #pragma unroll
    for (int kt = 0; kt < 2; ++kt) {
        const int f = kt * 32 + q * 8;
        const float4 waA = *(const float4*)(W0 + f);
        const float4 waB = *(const float4*)(W0 + f + 4);
        const float4 wbA = *(const float4*)(W0 + 64 + f);
        const float4 wbB = *(const float4*)(W0 + 64 + f + 4);
        const float4 bbA = *(const float4*)(b0 + f);
        const float4 bbB = *(const float4*)(b0 + f + 4);
        const float wa[8] = {waA.x, waA.y, waA.z, waA.w, waB.x, waB.y, waB.z, waB.w};
        const float wb[8] = {wbA.x, wbA.y, wbA.z, wbA.w, wbB.x, wbB.y, wbB.z, wbB.w};
        const float bb[8] = {bbA.x, bbA.y, bbA.z, bbA.w, bbB.x, bbB.y, bbB.z, bbB.w};
        float h0v[8], t0v[8];
        #pragma unroll
        for (int j = 0; j < 8; ++j) {
            const float z0 = fmaf(x0, wa[j], fmaf(x1, wb[j], bb[j]));
            const float h0 = fast_tanh(z0);
            h0v[j] = h0;
            t0v[j] = fmaf(-h0, h0, 1.0f) * wb[j];
        }
        union { unsigned int u[4]; half8 h; } ph, pt;
        #pragma unroll
        for (int p = 0; p < 4; ++p) {
            ph.u[p] = pk2(h0v[2 * p], h0v[2 * p + 1]);
            pt.u[p] = pk2(t0v[2 * p], t0v[2 * p + 1]);
        }
        // frag h-pair words double as the h0 staging format (2 features/uint)
        *(uint4*)&lds2[(wrow + r) * LDSW2 + kt * 16 + q * 4] = *(const uint4*)ph.u;
        ah0[kt] = ph.h; at0[kt] = pt.h;
    }

    // ---------------- GEMM1: z1 = h0 @ W1 ; tz1 = th0 @ W1
    f32x4 acc[4], tacc[4];
    #pragma unroll
    for (int nt = 0; nt < 4; ++nt) { acc[nt] = (f32x4){0,0,0,0}; tacc[nt] = (f32x4){0,0,0,0}; }
    #pragma unroll
    for (int kt = 0; kt < 2; ++kt)
        #pragma unroll
        for (int nt = 0; nt < 4; ++nt) {
            const half8 bw = ldpk(0, kt, nt);
            acc[nt]  = __builtin_amdgcn_mfma_f32_16x16x32_f16(ah0[kt], bw, acc[nt], 0, 0, 0);
            tacc[nt] = __builtin_amdgcn_mfma_f32_16x16x32_f16(at0[kt], bw, tacc[nt], 0, 0, 0);
        }

    // ---------------- P1: h1/th1 at (sample=q*4+g, f1=nt*16+r); keep + LDS
    unsigned int h1p[4][4];
    #pragma unroll
    for (int nt = 0; nt < 4; ++nt) {
        const float b1f = b1[nt * 16 + r];
        #pragma unroll
        for (int g = 0; g < 4; ++g) {
            const float z1 = acc[nt][g] + b1f;
            const float h1 = fast_tanh(z1);
            const float th1 = fmaf(-h1, h1, 1.0f) * tacc[nt][g];
            const unsigned int u = pk2(h1, th1);
            h1p[nt][g] = u;
            lds[(wrow + q * 4 + g) * LDSW + nt * 16 + r] = u;
        }
    }
    __builtin_amdgcn_wave_barrier();

    // ---------------- GEMM2: z2 = h1 @ W2 ; tz2 = th1 @ W2
    #pragma unroll
    for (int nt = 0; nt < 4; ++nt) { acc[nt] = (f32x4){0,0,0,0}; tacc[nt] = (f32x4){0,0,0,0}; }
    #pragma unroll
    for (int kt = 0; kt < 2; ++kt) {
        half8 av, at;
        ldfrag(wrow + r, kt, av, at);
        #pragma unroll
        for (int nt = 0; nt < 4; ++nt) {
            const half8 bw = ldpk(1, kt, nt);
            acc[nt]  = __builtin_amdgcn_mfma_f32_16x16x32_f16(av, bw, acc[nt], 0, 0, 0);
            tacc[nt] = __builtin_amdgcn_mfma_f32_16x16x32_f16(at, bw, tacc[nt], 0, 0, 0);
        }
    }
    __builtin_amdgcn_wave_barrier();

    // ---------------- P2: dz2 = W3*A2 ; tdz2 = -2*h2*dz2*tz2 -> LDS
    #pragma unroll
    for (int nt = 0; nt < 4; ++nt) {
        const float b2f = b2[nt * 16 + r];
        const float w3f = W3[nt * 16 + r];
        #pragma unroll
        for (int g = 0; g < 4; ++g) {
            const float z2 = acc[nt][g] + b2f;
            const float h2 = fast_tanh(z2);
            const float A2 = fmaf(-h2, h2, 1.0f);
            const float dz2 = w3f * A2;
            const float t1  = h2 * tacc[nt][g];
            const float td2 = -2.0f * (dz2 * t1);
            lds[(wrow + q * 4 + g) * LDSW + nt * 16 + r] = pk2(dz2, td2);
        }
    }
    __builtin_amdgcn_wave_barrier();

    // ---------------- GEMM3: g1 = dz2 @ W2T ; tg1 = tdz2 @ W2T
    #pragma unroll
    for (int nt = 0; nt < 4; ++nt) { acc[nt] = (f32x4){0,0,0,0}; tacc[nt] = (f32x4){0,0,0,0}; }
    #pragma unroll
    for (int kt = 0; kt < 2; ++kt) {
        half8 av, at;
        ldfrag(wrow + r, kt, av, at);
        #pragma unroll
        for (int nt = 0; nt < 4; ++nt) {
            const half8 bw = ldpk(2, kt, nt);
            acc[nt]  = __builtin_amdgcn_mfma_f32_16x16x32_f16(av, bw, acc[nt], 0, 0, 0);
            tacc[nt] = __builtin_amdgcn_mfma_f32_16x16x32_f16(at, bw, tacc[nt], 0, 0, 0);
        }
    }
    __builtin_amdgcn_wave_barrier();

    // ---------------- P3: dz1 = g1*A1 ; tdz1 = tg1*A1 - 2*g1*h1*th1 -> LDS
    #pragma unroll
    for (int nt = 0; nt < 4; ++nt)
        #pragma unroll
        for (int g = 0; g < 4; ++g) {
            const float g1 = acc[nt][g];
            const float tg1 = tacc[nt][g];
            const float2 ht = unpk2(h1p[nt][g]);
            const float A1 = fmaf(-ht.x, ht.x, 1.0f);
            const float d1 = g1 * A1;
            const float u = g1 * ht.x * ht.y;
            const float td1 = fmaf(tg1, A1, -2.0f * u);
            lds[(wrow + q * 4 + g) * LDSW + nt * 16 + r] = pk2(d1, td1);
        }
    __builtin_amdgcn_wave_barrier();

    // ---------------- GEMM4 (transposed): g0T = W1 @ dz1T ; tg0T = W1 @ tdz1T
    #pragma unroll
    for (int mt = 0; mt < 4; ++mt) { acc[mt] = (f32x4){0,0,0,0}; tacc[mt] = (f32x4){0,0,0,0}; }
    #pragma unroll
    for (int kt = 0; kt < 2; ++kt) {
        half8 bd, btd;
        ldfrag(wrow + r, kt, bd, btd);
        #pragma unroll
        for (int mt = 0; mt < 4; ++mt) {
            const half8 aw = ldpk(3, kt, mt);
            acc[mt]  = __builtin_amdgcn_mfma_f32_16x16x32_f16(aw, bd,  acc[mt], 0, 0, 0);
            tacc[mt] = __builtin_amdgcn_mfma_f32_16x16x32_f16(aw, btd, tacc[mt], 0, 0, 0);
        }
    }

    // ---------------- P4: read staged h0 pairs, recompute th0 = (1-h0^2)*wb,
    // fold into 3 dots; reduce over features: 16 in-lane + shfl_xor(16,32).
    float pg = 0.f, ph0 = 0.f, ph1 = 0.f;
    #pragma unroll
    for (int mt = 0; mt < 4; ++mt) {
        const int f = mt * 16 + q * 4;
        const float4 waF = *(const float4*)(W0 + f);
        const float4 wbF = *(const float4*)(W0 + 64 + f);
        const float wa[4] = {waF.x, waF.y, waF.z, waF.w};
        const float wb[4] = {wbF.x, wbF.y, wbF.z, wbF.w};
        // features f..f+3 = 2 packed uints at col mt*8 + q*2
        const uint2 hh = *(const uint2*)&lds2[(wrow + r) * LDSW2 + mt * 8 + q * 2];
        const float2 hA = unpk2(hh.x);   // h0 for g=0,1
        const float2 hB = unpk2(hh.y);   // h0 for g=2,3
        const float h0v[4] = {hA.x, hA.y, hB.x, hB.y};
        #pragma unroll
        for (int g = 0; g < 4; ++g) {
            const float h0 = h0v[g];
            const float A0 = fmaf(-h0, h0, 1.0f);
            const float th0 = A0 * wb[g];
            const float g0 = acc[mt][g];
            const float tg0 = tacc[mt][g];
            const float d0 = g0 * A0;
            const float u = g0 * h0 * th0;
            const float td0 = fmaf(-2.0f, u, tg0 * A0);
            pg  = fmaf(wa[g], d0, pg);
            ph0 = fmaf(wa[g], td0, ph0);
            ph1 = fmaf(wb[g], td0, ph1);
        }
    }
    pg  += __shfl_xor(pg, 16);  pg  += __shfl_xor(pg, 32);
    ph0 += __shfl_xor(ph0, 16); ph0 += __shfl_xor(ph0, 32);
    ph1 += __shfl_xor(ph1, 16); ph1 += __shfl_xor(ph1, 32);
    if (q == 0) {
        const float num = fmaf(-ph0, x1, pg);
        const float a = num / (ph1 + EPSL);
        float2 o;
        o.x = x1;
        o.y = a;
        *(float2*)(out + 2 * (sbase + r)) = o;
    }
}

extern "C" void kernel_launch(void* const* d_in, const int* in_sizes, int n_in,
                              void* d_out, int out_size, void* d_ws, size_t ws_size,
                              hipStream_t stream) {
    // setup_inputs order: t, x, W0, b0, W1, b1, W2, b2, W3, b3
    const float* x  = (const float*)d_in[1];
    const float* W0 = (const float*)d_in[2];
    const float* b0 = (const float*)d_in[3];
    const float* W1 = (const float*)d_in[4];
    const float* b1 = (const float*)d_in[5];
    const float* W2 = (const float*)d_in[6];
    const float* b2 = (const float*)d_in[7];
    const float* W3 = (const float*)d_in[8];
    // b3 unused (no effect on grad/Hessian)

    _Float16* pk = (_Float16*)d_ws;   // 4 mats * 4096 halfs = 32 KB
    const int B = in_sizes[1] / 2;    // 1048576

    pack_weights<<<1, 64, 0, stream>>>(W1, W2, pk);
    // 256-thread blocks = 4 independent waves x 16 samples each
    lnn_mfma<<<B / 64, 256, 0, stream>>>(x, W0, b0, b1, b2, W3, pk, (float*)d_out);
}